// Round 5
// baseline (1388.220 us; speedup 1.0000x reference)
//
#include <hip/hip_runtime.h>
#include <hip/hip_bf16.h>

#define BATCH 64
#define SEQ   512
#define INPD  128
#define HID   256
#define G4    1024   // 4*HID
#define HPAD  68     // h row-slice stride in floats (17 float4s) -> conflict-free b128 reads
#define HBUFSZ (16 * HPAD)

// 256 blocks x 512 threads. Block = (batch b, part p): owns 64 hidden units,
// 256 gate columns. Thread (CG = tid>>4: 8 cols, S = tid&15: k-slice of
// 16 h-rows + 8 x-rows). Weights in regs (192 f32/thread).
// Per step (2 barriers):
//   A: h-matvec from hbuf[st&1] (conflict-free b128) on top of acc (= x-part,
//      set last step) -> in-wave shfl_xor butterfly over 16 S-lanes ->
//      S==0 lane: bias+activation -> act[] (2x float4).
//   barrier
//   C+P: tid<64: gate read, cs/hn update, tagged atomic store, hbuf-next own,
//      out store. tid 64..255: poll partners (load-early / xpart / spin-late),
//      hbuf-next remote. All: xpart re-init acc for st+1.
//   barrier
// Cross-block h exchange: step-tagged 64-bit relaxed agent-scope atomics,
// double-buffered by parity (value-carried ordering, no fences).

#define HF(hv, rb) { \
    acc0 = fmaf(hv, wh[(rb)*8+0], acc0); acc1 = fmaf(hv, wh[(rb)*8+1], acc1); \
    acc2 = fmaf(hv, wh[(rb)*8+2], acc2); acc3 = fmaf(hv, wh[(rb)*8+3], acc3); \
    acc4 = fmaf(hv, wh[(rb)*8+4], acc4); acc5 = fmaf(hv, wh[(rb)*8+5], acc5); \
    acc6 = fmaf(hv, wh[(rb)*8+6], acc6); acc7 = fmaf(hv, wh[(rb)*8+7], acc7); }

#define XSET(xv) { \
    acc0 = xv * wi[0]; acc1 = xv * wi[1]; acc2 = xv * wi[2]; acc3 = xv * wi[3]; \
    acc4 = xv * wi[4]; acc5 = xv * wi[5]; acc6 = xv * wi[6]; acc7 = xv * wi[7]; }

#define XF(xv, rb) { \
    acc0 = fmaf(xv, wi[(rb)*8+0], acc0); acc1 = fmaf(xv, wi[(rb)*8+1], acc1); \
    acc2 = fmaf(xv, wi[(rb)*8+2], acc2); acc3 = fmaf(xv, wi[(rb)*8+3], acc3); \
    acc4 = fmaf(xv, wi[(rb)*8+4], acc4); acc5 = fmaf(xv, wi[(rb)*8+5], acc5); \
    acc6 = fmaf(xv, wi[(rb)*8+6], acc6); acc7 = fmaf(xv, wi[(rb)*8+7], acc7); }

#define XPART_ALL { \
    XSET(nx0.x) XF(nx0.y, 1) XF(nx0.z, 2) XF(nx0.w, 3) \
    XF(nx1.x, 4) XF(nx1.y, 5) XF(nx1.z, 6) XF(nx1.w, 7) }

#define BFLY(m) { \
    acc0 += __shfl_xor(acc0, m); acc1 += __shfl_xor(acc1, m); \
    acc2 += __shfl_xor(acc2, m); acc3 += __shfl_xor(acc3, m); \
    acc4 += __shfl_xor(acc4, m); acc5 += __shfl_xor(acc5, m); \
    acc6 += __shfl_xor(acc6, m); acc7 += __shfl_xor(acc7, m); }

__global__ __launch_bounds__(512, 2)
void ChaoticLSTM_kernel(const float* __restrict__ x,  const float* __restrict__ Wi,
                        const float* __restrict__ Wh, const float* __restrict__ Bb,
                        float* __restrict__ out, unsigned long long* __restrict__ exch)
{
    const int bid   = blockIdx.x;
    const int xcd   = bid & 7;
    const int slotn = bid >> 3;
    const int b     = xcd * 8 + (slotn >> 2);  // batch element
    const int part  = slotn & 3;               // 64-unit chunk of H
    const int tid   = threadIdx.x;
    const int CG    = tid >> 4;                // 0..31: column group (8 cols)
    const int S     = tid & 15;                // 0..15: k-slice
    const int g     = CG >> 3;                 // gate of this thread's columns
    const int jj0   = (CG & 7) * 8;
    const int gcol0 = g * 256 + part * 64 + jj0;

    __shared__ __align__(16) float hbuf[2][HBUFSZ];
    __shared__ __align__(16) float act[256];

    // ---- weights into registers (static indexing throughout) ----
    float wh[128];   // [r<16][cc<8] : h-rows S*16..S*16+15
    float wi[64];    // [r<8][cc<8]  : x-rows S*8..S*8+7
#pragma unroll
    for (int r = 0; r < 16; ++r) {
        const float* p = Wh + (size_t)(S * 16 + r) * G4 + gcol0;
        float4 u0 = *(const float4*)p;
        float4 u1 = *(const float4*)(p + 4);
        wh[r*8+0] = u0.x; wh[r*8+1] = u0.y; wh[r*8+2] = u0.z; wh[r*8+3] = u0.w;
        wh[r*8+4] = u1.x; wh[r*8+5] = u1.y; wh[r*8+6] = u1.z; wh[r*8+7] = u1.w;
    }
#pragma unroll
    for (int r = 0; r < 8; ++r) {
        const float* p = Wi + (size_t)(S * 8 + r) * G4 + gcol0;
        float4 u0 = *(const float4*)p;
        float4 u1 = *(const float4*)(p + 4);
        wi[r*8+0] = u0.x; wi[r*8+1] = u0.y; wi[r*8+2] = u0.z; wi[r*8+3] = u0.w;
        wi[r*8+4] = u1.x; wi[r*8+5] = u1.y; wi[r*8+6] = u1.z; wi[r*8+7] = u1.w;
    }
    float4 bq0 = *(const float4*)(Bb + gcol0);
    float4 bq1 = *(const float4*)(Bb + gcol0 + 4);

    unsigned long long* __restrict__ exb = exch + (size_t)b * 512;
    const float* __restrict__ xrow = x + (size_t)b * SEQ * INPD + S * 8;

    // ---- init ----
    float cs = 0.f, hn_last = 0.f;
    if (tid < 256) hbuf[0][(tid >> 4) * HPAD + (tid & 15)] = 0.f;
    if (tid < 64) {   // clear own exchange slots (both parities)
        __hip_atomic_store(&exb[part*64 + tid],       0ull, __ATOMIC_RELAXED, __HIP_MEMORY_SCOPE_AGENT);
        __hip_atomic_store(&exb[256 + part*64 + tid], 0ull, __ATOMIC_RELAXED, __HIP_MEMORY_SCOPE_AGENT);
    }

    float acc0, acc1, acc2, acc3, acc4, acc5, acc6, acc7;
    {   // acc = x-part for step 0
        float4 nx0 = *(const float4*)(xrow);
        float4 nx1 = *(const float4*)(xrow + 4);
        XPART_ALL;
    }
    __syncthreads();

    for (int st = 0; st < SEQ; ++st) {
        // issue x loads for step st+1 early (consumed at slot end)
        const float* xp = xrow + (size_t)((st + 1 < SEQ) ? st + 1 : st) * INPD;
        float4 nx0 = *(const float4*)(xp);
        float4 nx1 = *(const float4*)(xp + 4);

        // ---- Slot A: h-matvec (conflict-free b128 broadcast reads) ----
        {
            const float* hb = hbuf[st & 1] + S * HPAD;
            float4 hv;
            hv = *(const float4*)(hb);
            HF(hv.x, 0)  HF(hv.y, 1)  HF(hv.z, 2)  HF(hv.w, 3)
            hv = *(const float4*)(hb + 4);
            HF(hv.x, 4)  HF(hv.y, 5)  HF(hv.z, 6)  HF(hv.w, 7)
            hv = *(const float4*)(hb + 8);
            HF(hv.x, 8)  HF(hv.y, 9)  HF(hv.z, 10) HF(hv.w, 11)
            hv = *(const float4*)(hb + 12);
            HF(hv.x, 12) HF(hv.y, 13) HF(hv.z, 14) HF(hv.w, 15)
        }
        // in-wave butterfly reduce over the 16 S-lanes of this CG
        BFLY(1) BFLY(2) BFLY(4) BFLY(8)

        if ((tid & 15) == 0) {   // one lane per CG finalizes its 8 columns
            float s0 = acc0 + bq0.x, s1 = acc1 + bq0.y, s2 = acc2 + bq0.z, s3 = acc3 + bq0.w;
            float s4 = acc4 + bq1.x, s5 = acc5 + bq1.y, s6 = acc6 + bq1.z, s7 = acc7 + bq1.w;
            float a0, a1, a2, a3, a4, a5, a6, a7;
            if (g == 2) {
                a0 = tanhf(s0); a1 = tanhf(s1); a2 = tanhf(s2); a3 = tanhf(s3);
                a4 = tanhf(s4); a5 = tanhf(s5); a6 = tanhf(s6); a7 = tanhf(s7);
            } else {
                a0 = 1.f/(1.f+expf(-s0)); a1 = 1.f/(1.f+expf(-s1));
                a2 = 1.f/(1.f+expf(-s2)); a3 = 1.f/(1.f+expf(-s3));
                a4 = 1.f/(1.f+expf(-s4)); a5 = 1.f/(1.f+expf(-s5));
                a6 = 1.f/(1.f+expf(-s6)); a7 = 1.f/(1.f+expf(-s7));
            }
            *(float4*)(act + CG*8)     = make_float4(a0, a1, a2, a3);
            *(float4*)(act + CG*8 + 4) = make_float4(a4, a5, a6, a7);
        }
        __syncthreads();

        // ---- Slot C+P: update, exchange, xpart for st+1 ----
        const unsigned tag = (unsigned)(st + 1);
        unsigned long long* slotp = exb + (st & 1) * 256;
        float* hbn = hbuf[(st + 1) & 1];
        if (tid < 64) {
            float iv = act[tid], fv = act[64 + tid], gv = act[128 + tid], ov = act[192 + tid];
            cs = fv * cs + iv * gv;
            float hn = ov * tanhf(cs);
            hn_last = hn;
            int j = part * 64 + tid;
            unsigned long long w = ((unsigned long long)tag << 32)
                                 | (unsigned long long)__float_as_uint(hn);
            __hip_atomic_store(&slotp[j], w, __ATOMIC_RELAXED, __HIP_MEMORY_SCOPE_AGENT);
            hbn[(j >> 4) * HPAD + (tid & 15)] = hn;
            out[(size_t)(b * SEQ + st) * HID + j] = hn;
        }
        unsigned long long v = 0; int idx = 0;
        const bool poller = (tid >= 64) && (tid < 256) && (st + 1 < SEQ);
        if (poller) {
            int q  = tid >> 6;                  // 1..3
            idx = ((part + q) & 3) * 64 + (tid & 63);
            v = __hip_atomic_load(&slotp[idx], __ATOMIC_RELAXED, __HIP_MEMORY_SCOPE_AGENT);
        }
        if (st + 1 < SEQ) { XPART_ALL }         // re-init acc for st+1 (all threads)
        if (poller) {
            while ((unsigned)(v >> 32) != tag)
                v = __hip_atomic_load(&slotp[idx], __ATOMIC_RELAXED, __HIP_MEMORY_SCOPE_AGENT);
            hbn[(idx >> 4) * HPAD + (idx & 15)] = __uint_as_float((unsigned)v);
        }
        __syncthreads();
    }

    // ---- epilogue: ht, ct ----
    if (tid < 64) {
        int j = part * 64 + tid;
        size_t base = (size_t)BATCH * SEQ * HID;
        out[base + (size_t)b * HID + j] = hn_last;
        out[base + (size_t)BATCH * HID + (size_t)b * HID + j] = cs;
    }
}

extern "C" void kernel_launch(void* const* d_in, const int* in_sizes, int n_in,
                              void* d_out, int out_size, void* d_ws, size_t ws_size,
                              hipStream_t stream) {
    const float* x  = (const float*)d_in[0];
    const float* Wi = (const float*)d_in[1];
    const float* Wh = (const float*)d_in[2];
    const float* B  = (const float*)d_in[3];
    float* out = (float*)d_out;
    unsigned long long* exch = (unsigned long long*)d_ws;   // 64*512*8 = 256 KB

    ChaoticLSTM_kernel<<<dim3(256), dim3(512), 0, stream>>>(x, Wi, Wh, B, out, exch);
}

// Round 6
// 853.306 us; speedup vs baseline: 1.6269x; 1.6269x over previous
//
#include <hip/hip_runtime.h>
#include <hip/hip_bf16.h>

#define BATCH 64
#define SEQ   512
#define INPD  128
#define HID   256
#define G4    1024   // 4*HID
#define HPAD  68     // h row stride (floats): 68 mod 32 = 4 -> b128 reads 2-way max (free)
#define PSS   260    // ps row stride (floats): 260 mod 32 = 4 -> all ps accesses 2-way max (free)

// 256 blocks x 512 threads. Block = (batch b, part p): owns 64 hidden units =
// 256 gate columns. Thread (CG = tid>>4: 8 cols, S = tid&15: k-slice of
// 16 h-rows + 8 x-rows). Weights in regs: wh[16][8], wi[8][8] (192 f32/thread).
// Per step (3 barriers, every LDS access <=2-way bank aliasing = free):
//   A: h-matvec from hs (4x b128, stride HPAD) on top of acc (= x-part set
//      last step) -> 8 partials -> ps (2x b128, stride PSS).
//   barrier
//   B: tid<256: read 16 partials (b32, free), +bias, ONE transcendental,
//      act[c]. tid>=256: XPART for st+1 (hidden in this slot).
//   barrier
//   C: wave0 (tid<64): gates -> cs/hn, tagged atomic store FIRST, hs & out
//      writes, then XPART. waves1-3: poll partners (load-early/XPART/spin-late),
//      write hs. waves4-7: nothing (XPART already done).
//   barrier
// Cross-block h exchange: step-tagged 64-bit relaxed agent-scope atomics,
// double-buffered by parity (value-carried ordering, no fences needed).

#define HF(hv, rb) { \
    acc0 = fmaf(hv, wh[(rb)*8+0], acc0); acc1 = fmaf(hv, wh[(rb)*8+1], acc1); \
    acc2 = fmaf(hv, wh[(rb)*8+2], acc2); acc3 = fmaf(hv, wh[(rb)*8+3], acc3); \
    acc4 = fmaf(hv, wh[(rb)*8+4], acc4); acc5 = fmaf(hv, wh[(rb)*8+5], acc5); \
    acc6 = fmaf(hv, wh[(rb)*8+6], acc6); acc7 = fmaf(hv, wh[(rb)*8+7], acc7); }

#define XSET(xv) { \
    acc0 = xv * wi[0]; acc1 = xv * wi[1]; acc2 = xv * wi[2]; acc3 = xv * wi[3]; \
    acc4 = xv * wi[4]; acc5 = xv * wi[5]; acc6 = xv * wi[6]; acc7 = xv * wi[7]; }

#define XF(xv, rb) { \
    acc0 = fmaf(xv, wi[(rb)*8+0], acc0); acc1 = fmaf(xv, wi[(rb)*8+1], acc1); \
    acc2 = fmaf(xv, wi[(rb)*8+2], acc2); acc3 = fmaf(xv, wi[(rb)*8+3], acc3); \
    acc4 = fmaf(xv, wi[(rb)*8+4], acc4); acc5 = fmaf(xv, wi[(rb)*8+5], acc5); \
    acc6 = fmaf(xv, wi[(rb)*8+6], acc6); acc7 = fmaf(xv, wi[(rb)*8+7], acc7); }

#define XPART_ALL { \
    XSET(nx0.x) XF(nx0.y, 1) XF(nx0.z, 2) XF(nx0.w, 3) \
    XF(nx1.x, 4) XF(nx1.y, 5) XF(nx1.z, 6) XF(nx1.w, 7) }

__global__ __launch_bounds__(512, 2)
void ChaoticLSTM_kernel(const float* __restrict__ x,  const float* __restrict__ Wi,
                        const float* __restrict__ Wh, const float* __restrict__ Bb,
                        float* __restrict__ out, unsigned long long* __restrict__ exch)
{
    const int bid   = blockIdx.x;
    const int xcd   = bid & 7;
    const int slotn = bid >> 3;
    const int b     = xcd * 8 + (slotn >> 2);  // batch element
    const int part  = slotn & 3;               // 64-unit chunk of H
    const int tid   = threadIdx.x;
    const int CG    = tid >> 4;                // 0..31: column group (8 cols)
    const int S     = tid & 15;                // 0..15: k-slice
    const int g     = CG >> 3;
    const int jj0   = (CG & 7) * 8;
    const int gcol0 = g * 256 + part * 64 + jj0;

    __shared__ __align__(16) float hs[16 * HPAD];
    __shared__ __align__(16) float ps[16 * PSS];
    __shared__ __align__(16) float act[256];

    // ---- weights into registers (static indexing throughout) ----
    float wh[128];   // [r<16][cc<8] : h-rows S*16..S*16+15
    float wi[64];    // [r<8][cc<8]  : x-rows S*8..S*8+7
#pragma unroll
    for (int r = 0; r < 16; ++r) {
        const float* p = Wh + (size_t)(S * 16 + r) * G4 + gcol0;
        float4 u0 = *(const float4*)p;
        float4 u1 = *(const float4*)(p + 4);
        wh[r*8+0] = u0.x; wh[r*8+1] = u0.y; wh[r*8+2] = u0.z; wh[r*8+3] = u0.w;
        wh[r*8+4] = u1.x; wh[r*8+5] = u1.y; wh[r*8+6] = u1.z; wh[r*8+7] = u1.w;
    }
#pragma unroll
    for (int r = 0; r < 8; ++r) {
        const float* p = Wi + (size_t)(S * 8 + r) * G4 + gcol0;
        float4 u0 = *(const float4*)p;
        float4 u1 = *(const float4*)(p + 4);
        wi[r*8+0] = u0.x; wi[r*8+1] = u0.y; wi[r*8+2] = u0.z; wi[r*8+3] = u0.w;
        wi[r*8+4] = u1.x; wi[r*8+5] = u1.y; wi[r*8+6] = u1.z; wi[r*8+7] = u1.w;
    }
    const float Bred = (tid < 256) ? Bb[(tid >> 6) * 256 + part * 64 + (tid & 63)] : 0.f;

    unsigned long long* __restrict__ exb = exch + (size_t)b * 512;
    const float* __restrict__ xrow = x + (size_t)b * SEQ * INPD + S * 8;

    // ---- init ----
    float cs = 0.f, hn_last = 0.f;
    if (tid < 256) hs[(tid >> 4) * HPAD + (tid & 15)] = 0.f;
    if (tid < 64) {   // clear own exchange slots (both parities)
        __hip_atomic_store(&exb[part*64 + tid],       0ull, __ATOMIC_RELAXED, __HIP_MEMORY_SCOPE_AGENT);
        __hip_atomic_store(&exb[256 + part*64 + tid], 0ull, __ATOMIC_RELAXED, __HIP_MEMORY_SCOPE_AGENT);
    }

    float acc0, acc1, acc2, acc3, acc4, acc5, acc6, acc7;
    {   // acc = x-part for step 0
        float4 nx0 = *(const float4*)(xrow);
        float4 nx1 = *(const float4*)(xrow + 4);
        XPART_ALL;
    }
    __syncthreads();

    for (int st = 0; st < SEQ; ++st) {
        // issue x loads for step st+1 early (consumed in phase B/C XPART)
        const float* xp = xrow + (size_t)((st + 1 < SEQ) ? st + 1 : st) * INPD;
        float4 nx0 = *(const float4*)(xp);
        float4 nx1 = *(const float4*)(xp + 4);

        // ---- Phase A: h-matvec (conflict-free b128 reads) + ps write ----
        {
            const float* hb = hs + S * HPAD;
            float4 hv;
            hv = *(const float4*)(hb);
            HF(hv.x, 0)  HF(hv.y, 1)  HF(hv.z, 2)  HF(hv.w, 3)
            hv = *(const float4*)(hb + 4);
            HF(hv.x, 4)  HF(hv.y, 5)  HF(hv.z, 6)  HF(hv.w, 7)
            hv = *(const float4*)(hb + 8);
            HF(hv.x, 8)  HF(hv.y, 9)  HF(hv.z, 10) HF(hv.w, 11)
            hv = *(const float4*)(hb + 12);
            HF(hv.x, 12) HF(hv.y, 13) HF(hv.z, 14) HF(hv.w, 15)
        }
        *(float4*)(ps + S * PSS + CG * 8)     = make_float4(acc0, acc1, acc2, acc3);
        *(float4*)(ps + S * PSS + CG * 8 + 4) = make_float4(acc4, acc5, acc6, acc7);
        __syncthreads();

        // ---- Phase B: reduce + activation (tid<256); XPART (tid>=256) ----
        if (tid < 256) {
            const int c = tid;
            float t0 = ps[0*PSS+c]  + ps[1*PSS+c];
            float t1 = ps[2*PSS+c]  + ps[3*PSS+c];
            float t2 = ps[4*PSS+c]  + ps[5*PSS+c];
            float t3 = ps[6*PSS+c]  + ps[7*PSS+c];
            float t4 = ps[8*PSS+c]  + ps[9*PSS+c];
            float t5 = ps[10*PSS+c] + ps[11*PSS+c];
            float t6 = ps[12*PSS+c] + ps[13*PSS+c];
            float t7 = ps[14*PSS+c] + ps[15*PSS+c];
            float gs = Bred + (((t0 + t1) + (t2 + t3)) + ((t4 + t5) + (t6 + t7)));
            float a;
            if ((tid >> 6) == 2) a = tanhf(gs);       // wave-uniform branch
            else                 a = 1.f / (1.f + expf(-gs));
            act[c] = a;
        } else if (st + 1 < SEQ) {
            XPART_ALL;                                 // waves 4-7: st+1 x-part
        }
        __syncthreads();

        // ---- Phase C: update + exchange; tid<256 XPART in RTT window ----
        const unsigned tag = (unsigned)(st + 1);
        unsigned long long* slotp = exb + (st & 1) * 256;
        if (tid < 64) {
            float iv = act[tid], fv = act[64 + tid], gv = act[128 + tid], ov = act[192 + tid];
            cs = fv * cs + iv * gv;
            float hn = ov * tanhf(cs);
            hn_last = hn;
            int j = part * 64 + tid;
            unsigned long long w = ((unsigned long long)tag << 32)
                                 | (unsigned long long)__float_as_uint(hn);
            __hip_atomic_store(&slotp[j], w, __ATOMIC_RELAXED, __HIP_MEMORY_SCOPE_AGENT); // first
            hs[(j >> 4) * HPAD + (j & 15)] = hn;
            out[(size_t)(b * SEQ + st) * HID + j] = hn;
            if (st + 1 < SEQ) { XPART_ALL }
        } else if (tid < 256) {
            const bool live = (st + 1 < SEQ);
            unsigned long long v = 0; int idx = 0;
            if (live) {
                int q  = tid >> 6;                  // 1..3
                idx = ((part + q) & 3) * 64 + (tid & 63);
                v = __hip_atomic_load(&slotp[idx], __ATOMIC_RELAXED, __HIP_MEMORY_SCOPE_AGENT);
                XPART_ALL
                while ((unsigned)(v >> 32) != tag)
                    v = __hip_atomic_load(&slotp[idx], __ATOMIC_RELAXED, __HIP_MEMORY_SCOPE_AGENT);
                hs[(idx >> 4) * HPAD + (idx & 15)] = __uint_as_float((unsigned)v);
            }
        }
        __syncthreads();
    }

    // ---- epilogue: ht, ct ----
    if (tid < 64) {
        int j = part * 64 + tid;
        size_t base = (size_t)BATCH * SEQ * HID;
        out[base + (size_t)b * HID + j] = hn_last;
        out[base + (size_t)BATCH * HID + (size_t)b * HID + j] = cs;
    }
}

extern "C" void kernel_launch(void* const* d_in, const int* in_sizes, int n_in,
                              void* d_out, int out_size, void* d_ws, size_t ws_size,
                              hipStream_t stream) {
    const float* x  = (const float*)d_in[0];
    const float* Wi = (const float*)d_in[1];
    const float* Wh = (const float*)d_in[2];
    const float* B  = (const float*)d_in[3];
    float* out = (float*)d_out;
    unsigned long long* exch = (unsigned long long*)d_ws;   // 64*512*8 = 256 KB

    ChaoticLSTM_kernel<<<dim3(256), dim3(512), 0, stream>>>(x, Wi, Wh, B, out, exch);
}